// Round 6
// baseline (170033.386 us; speedup 1.0000x reference)
//
#include <hip/hip_runtime.h>
#include <math.h>

#define TSTEPS 512
#define NBATCH 256
#define DLL 300
#define DAA 74
#define DVV 35
#define DX  409
#define DH  128
#define DMEM 256
#define CST 768   // 6*DH

typedef unsigned short u16;
typedef unsigned int   u32;
typedef float v2f __attribute__((ext_vector_type(2)));

__device__ __forceinline__ float ulo(u32 u){ return __uint_as_float(u<<16); }
__device__ __forceinline__ float uhi(u32 u){ return __uint_as_float(u & 0xffff0000u); }
__device__ __forceinline__ float sigf(float x){ return 1.0f/(1.0f+expf(-x)); }

// dst[k*OUT + o] = bf16(src[o*IN + k])
__global__ void cast_transpose(const float* __restrict__ src, u16* __restrict__ dst,
                               int OUT, int IN){
  int idx = blockIdx.x*blockDim.x + threadIdx.x;
  int total = OUT*IN;
  if (idx >= total) return;
  int k = idx / OUT;
  int o = idx - k*OUT;
  float v = src[o*IN + k];
  u32 u = __float_as_uint(v);
  u32 r = (u + 0x7fffu + ((u>>16)&1u)) >> 16;   // RNE
  dst[idx] = (u16)r;
}

struct P {
  const float* x;
  const float *bih_l,*bhh_l,*bih_a,*bhh_a,*bih_v,*bhh_v;
  const float *a1b1,*a1b2,*a2b1,*a2b2,*g1b1,*g1b2,*g2b1,*g2b2;
  const float *ob1,*ow2,*ob2;
  const u16 *ihl,*hhl,*iha,*hha,*ihv,*hhv;
  const u16 *a1w1,*a1w2,*a2w1,*a2w2,*g1w1,*g1w2,*g2w1,*g2w2,*ow1;
  float* out;
};

// 128 blocks x 1024 threads. ROWS=2 rows/block. Full-K in-order sweeps split into
// 4 sequential kh-quarters (4 stream heads/block = 64/XCD; R1/R5-proven-clean shape).
// u32 loads: 2 output cols per load; rows share the load (4 MACs in OUT=512 phase).
__global__ void __launch_bounds__(1024)
mfn_persistent(P p){
  __shared__ __align__(16) float s_x2[820];      // [i*2+r], i<409
  __shared__ __align__(16) float s_h2[3][256];   // [m][u*2+r]
  __shared__ __align__(16) float s_c2[3][256];
  __shared__ __align__(16) float s_cstar[1536];  // [r*768+idx]
  __shared__ __align__(16) float s_z[512];       // [r*256+col]
  __shared__ __align__(16) float s_attm[2048];   // [r*1024 + (att768|mem256)]
  __shared__ __align__(16) float s_z2[1536];     // [r*768 + m*256+col]
  __shared__ __align__(16) float s_mem[512];     // [r*256+col]
  __shared__ __align__(16) float s_p[12288];     // partials (phase-specific layout)
  __shared__ __align__(16) float s_last[1280];   // [r*640+j]
  __shared__ __align__(16) float s_bl[3][512];   // LSTM bias (bih+bhh)
  __shared__ __align__(16) float s_a1b1[256];
  __shared__ __align__(16) float s_a1b2[768];
  __shared__ __align__(16) float s_b6[6][256];   // a2b1,g1b1,g2b1,a2b2,g1b2,g2b2
  __shared__ float s_red[8];

  const int tid = threadIdx.x;
  const int n0  = blockIdx.x*2;

  // ---- init: biases to LDS, zero state, load x(0) ----
  if (tid < 512){
    s_bl[0][tid]=p.bih_l[tid]+p.bhh_l[tid];
    s_bl[1][tid]=p.bih_a[tid]+p.bhh_a[tid];
    s_bl[2][tid]=p.bih_v[tid]+p.bhh_v[tid];
    s_mem[tid]=0.f;
  }
  if (tid < 256){
    s_a1b1[tid]=p.a1b1[tid];
    s_b6[0][tid]=p.a2b1[tid]; s_b6[1][tid]=p.g1b1[tid]; s_b6[2][tid]=p.g2b1[tid];
    s_b6[3][tid]=p.a2b2[tid]; s_b6[4][tid]=p.g1b2[tid]; s_b6[5][tid]=p.g2b2[tid];
  }
  if (tid < 768){ s_a1b2[tid]=p.a1b2[tid]; (&s_h2[0][0])[tid]=0.f; (&s_c2[0][0])[tid]=0.f; }
  if (tid < 818) s_x2[tid] = p.x[(size_t)(n0+(tid&1))*DX + (tid>>1)];
  __syncthreads();

  for (int t=0; t<TSTEPS; t++){
    // ================ P1: LSTM gate sweeps (uc=tid&255 col-pair, kh=tid>>8 quarter) ======
    {
      const int uc=tid&255, kh=tid>>8;
      float a00,a01,a10,a11;
      // ---- L ----
      a00=0.f;a01=0.f;a10=0.f;a11=0.f;
      {
        const u32* __restrict__ w=(const u32*)p.ihl + uc;
        int k1=75*(kh+1);
        #pragma unroll 4
        for (int k=75*kh;k<k1;++k){
          v2f xv=*(const v2f*)&s_x2[k*2];
          u32 u=w[(size_t)k<<8];
          float w0=ulo(u), w1=uhi(u);
          a00+=xv.x*w0; a01+=xv.y*w0; a10+=xv.x*w1; a11+=xv.y*w1;
        }
        const u32* __restrict__ wh=(const u32*)p.hhl + uc;
        int h1=32*(kh+1);
        #pragma unroll 4
        for (int k=32*kh;k<h1;++k){
          v2f hv=*(const v2f*)&s_h2[0][k*2];
          u32 u=wh[(size_t)k<<8];
          float w0=ulo(u), w1=uhi(u);
          a00+=hv.x*w0; a01+=hv.y*w0; a10+=hv.x*w1; a11+=hv.y*w1;
        }
      }
      *(v2f*)&s_p[kh*1024 +       2*uc] = (v2f){a00,a10};
      *(v2f*)&s_p[kh*1024 + 512 + 2*uc] = (v2f){a01,a11};
      // ---- A ----
      a00=0.f;a01=0.f;a10=0.f;a11=0.f;
      {
        const u32* __restrict__ w=(const u32*)p.iha + uc;
        int k0=(DAA*kh)>>2, k1=(DAA*(kh+1))>>2;
        #pragma unroll 4
        for (int k=k0;k<k1;++k){
          v2f xv=*(const v2f*)&s_x2[(DLL+k)*2];
          u32 u=w[(size_t)k<<8];
          float w0=ulo(u), w1=uhi(u);
          a00+=xv.x*w0; a01+=xv.y*w0; a10+=xv.x*w1; a11+=xv.y*w1;
        }
        const u32* __restrict__ wh=(const u32*)p.hha + uc;
        int h1=32*(kh+1);
        #pragma unroll 4
        for (int k=32*kh;k<h1;++k){
          v2f hv=*(const v2f*)&s_h2[1][k*2];
          u32 u=wh[(size_t)k<<8];
          float w0=ulo(u), w1=uhi(u);
          a00+=hv.x*w0; a01+=hv.y*w0; a10+=hv.x*w1; a11+=hv.y*w1;
        }
      }
      *(v2f*)&s_p[4096 + kh*1024 +       2*uc] = (v2f){a00,a10};
      *(v2f*)&s_p[4096 + kh*1024 + 512 + 2*uc] = (v2f){a01,a11};
      // ---- V ----
      a00=0.f;a01=0.f;a10=0.f;a11=0.f;
      {
        const u32* __restrict__ w=(const u32*)p.ihv + uc;
        int k0=(DVV*kh)>>2, k1=(DVV*(kh+1))>>2;
        #pragma unroll 4
        for (int k=k0;k<k1;++k){
          v2f xv=*(const v2f*)&s_x2[(DLL+DAA+k)*2];
          u32 u=w[(size_t)k<<8];
          float w0=ulo(u), w1=uhi(u);
          a00+=xv.x*w0; a01+=xv.y*w0; a10+=xv.x*w1; a11+=xv.y*w1;
        }
        const u32* __restrict__ wh=(const u32*)p.hhv + uc;
        int h1=32*(kh+1);
        #pragma unroll 4
        for (int k=32*kh;k<h1;++k){
          v2f hv=*(const v2f*)&s_h2[2][k*2];
          u32 u=wh[(size_t)k<<8];
          float w0=ulo(u), w1=uhi(u);
          a00+=hv.x*w0; a01+=hv.y*w0; a10+=hv.x*w1; a11+=hv.y*w1;
        }
      }
      *(v2f*)&s_p[8192 + kh*1024 +       2*uc] = (v2f){a00,a10};
      *(v2f*)&s_p[8192 + kh*1024 + 512 + 2*uc] = (v2f){a01,a11};
    }
    __syncthreads();                                   // B1

    // x(t+1) prefetch into a register (written at P10)
    float xp=0.f;
    if (t+1 < TSTEPS && tid < 818)
      xp = p.x[(size_t)(t+1)*NBATCH*DX + (size_t)(n0+(tid&1))*DX + (tid>>1)];

    // ================ P2: LSTM activations (768 tasks) ================
    if (tid < 768){
      int m=tid>>8, rem=tid&255, u=rem>>1, r=rem&1;
      const float* pb = s_p + m*4096 + r*512;
      float g0=s_bl[m][u]     + pb[u]      +pb[1024+u]      +pb[2048+u]      +pb[3072+u];
      float g1=s_bl[m][128+u] + pb[128+u]  +pb[1024+128+u]  +pb[2048+128+u]  +pb[3072+128+u];
      float g2=s_bl[m][256+u] + pb[256+u]  +pb[1024+256+u]  +pb[2048+256+u]  +pb[3072+256+u];
      float g3=s_bl[m][384+u] + pb[384+u]  +pb[1024+384+u]  +pb[2048+384+u]  +pb[3072+384+u];
      float ig=sigf(g0), fg=sigf(g1), gg=tanhf(g2), og=sigf(g3);
      float co=s_c2[m][u*2+r];
      float c = fg*co + ig*gg;
      float h = og*tanhf(c);
      s_c2[m][u*2+r]=c; s_h2[m][u*2+r]=h;
      s_cstar[r*768 + m*128+u]       = co;
      s_cstar[r*768 + 384 + m*128+u] = c;
    }
    __syncthreads();                                   // B2

    // ================ P3: att1_W1 (K=768,OUT=256) ================
    {
      const int uc=tid&127, r=(tid>>7)&1, kh=tid>>8;
      float a0=0.f,a1=0.f;
      const u32* __restrict__ w=(const u32*)p.a1w1 + uc;
      const float* __restrict__ act=&s_cstar[r*768];
      int k1=192*(kh+1);
      #pragma unroll 8
      for (int k=192*kh;k<k1;++k){
        float av=act[k]; u32 u=w[(size_t)k<<7];
        a0+=av*ulo(u); a1+=av*uhi(u);
      }
      *(v2f*)&s_p[(kh*2+r)*256 + 2*uc] = (v2f){a0,a1};
    }
    __syncthreads();                                   // B3
    if (tid < 512){
      int r=tid>>8, col=tid&255;
      const float* q=s_p+r*256;
      float z=s_a1b1[col] + q[col]+q[512+col]+q[1024+col]+q[1536+col];
      s_z[r*256+col]=fmaxf(z,0.f);
    }
    __syncthreads();                                   // B4

    // ================ P5: att1_W2 (K=256,OUT=768) ================
    {
      const int uc=tid&127, r=(tid>>7)&1, kh=tid>>8;
      float a0=0.f,a1=0.f,b0=0.f,b1=0.f,c0=0.f,c1=0.f;
      const u32* __restrict__ w=(const u32*)p.a1w2 + uc;
      const float* __restrict__ act=&s_z[r*256];
      int k1=64*(kh+1);
      #pragma unroll 8
      for (int k=64*kh;k<k1;++k){
        float av=act[k];
        const u32* wb=w + (size_t)k*384;
        u32 u0=wb[0], u1=wb[128], u2=wb[256];
        a0+=av*ulo(u0); a1+=av*uhi(u0);
        b0+=av*ulo(u1); b1+=av*uhi(u1);
        c0+=av*ulo(u2); c1+=av*uhi(u2);
      }
      *(v2f*)&s_p[(kh*2+r)*768 +       2*uc] = (v2f){a0,a1};
      *(v2f*)&s_p[(kh*2+r)*768 + 256 + 2*uc] = (v2f){b0,b1};
      *(v2f*)&s_p[(kh*2+r)*768 + 512 + 2*uc] = (v2f){c0,c1};
    }
    __syncthreads();                                   // B5

    // ================ softmax + attended ================
    {
      const int r=tid>>8, col=tid&255;   // valid for tid<512
      float s0=-1e30f,s1=-1e30f,s2=-1e30f;
      if (tid<512){
        const float* q=s_p+r*768;
        s0=s_a1b2[col]     + q[col]      +q[1536+col]      +q[3072+col]      +q[4608+col];
        s1=s_a1b2[256+col] + q[256+col]  +q[1536+256+col]  +q[3072+256+col]  +q[4608+256+col];
        s2=s_a1b2[512+col] + q[512+col]  +q[1536+512+col]  +q[3072+512+col]  +q[4608+512+col];
      }
      float mx=fmaxf(fmaxf(s0,s1),s2);
      for (int off=32; off; off>>=1) mx=fmaxf(mx,__shfl_down(mx,off));
      if (tid<512 && (tid&63)==0) s_red[tid>>6]=mx;
      __syncthreads();                                 // B6
      float e0=0.f,e1=0.f,e2=0.f,ss=0.f;
      if (tid<512){
        int rb=r*4;
        float m=fmaxf(fmaxf(s_red[rb],s_red[rb+1]),fmaxf(s_red[rb+2],s_red[rb+3]));
        e0=expf(s0-m); e1=expf(s1-m); e2=expf(s2-m);
        ss=e0+e1+e2;
      }
      for (int off=32; off; off>>=1) ss+=__shfl_down(ss,off);
      __syncthreads();                                 // B7 (max reads done)
      if (tid<512 && (tid&63)==0) s_red[tid>>6]=ss;
      if (tid<512) s_attm[r*1024 + 768 + col] = s_mem[r*256+col];
      __syncthreads();                                 // B8
      if (tid<512){
        int rb=r*4;
        float inv=1.0f/(s_red[rb]+s_red[rb+1]+s_red[rb+2]+s_red[rb+3]);
        s_attm[r*1024 + col]       = e0*inv*s_cstar[r*768+col];
        s_attm[r*1024 + 256 + col] = e1*inv*s_cstar[r*768+256+col];
        s_attm[r*1024 + 512 + col] = e2*inv*s_cstar[r*768+512+col];
      }
    }
    __syncthreads();                                   // B9

    // ================ P7: att2/g1/g2 layer-1 (3 sequential sweeps) ================
    {
      const int uc=tid&127, r=(tid>>7)&1, kh=tid>>8;
      const float* __restrict__ ar=&s_attm[r*1024];
      float a0,a1;
      a0=0.f;a1=0.f;
      {
        const u32* __restrict__ w=(const u32*)p.a2w1 + uc;
        int k1=192*(kh+1);
        #pragma unroll 8
        for (int k=192*kh;k<k1;++k){ float av=ar[k]; u32 u=w[(size_t)k<<7]; a0+=av*ulo(u); a1+=av*uhi(u); }
      }
      *(v2f*)&s_p[(kh*2+r)*256 + 2*uc] = (v2f){a0,a1};
      a0=0.f;a1=0.f;
      {
        const u32* __restrict__ w=(const u32*)p.g1w1 + uc;
        int k1=256*(kh+1);
        #pragma unroll 8
        for (int k=256*kh;k<k1;++k){ float av=ar[k]; u32 u=w[(size_t)k<<7]; a0+=av*ulo(u); a1+=av*uhi(u); }
      }
      *(v2f*)&s_p[2048 + (kh*2+r)*256 + 2*uc] = (v2f){a0,a1};
      a0=0.f;a1=0.f;
      {
        const u32* __restrict__ w=(const u32*)p.g2w1 + uc;
        int k1=256*(kh+1);
        #pragma unroll 8
        for (int k=256*kh;k<k1;++k){ float av=ar[k]; u32 u=w[(size_t)k<<7]; a0+=av*ulo(u); a1+=av*uhi(u); }
      }
      *(v2f*)&s_p[4096 + (kh*2+r)*256 + 2*uc] = (v2f){a0,a1};
    }
    __syncthreads();                                   // B10
    // z2 finalize (1536 tasks)
    for (int i=tid;i<1536;i+=1024){
      int r=(i>=768)?1:0, j=i-r*768, m=j>>8, col=j&255;
      const float* q=s_p+m*2048+r*256;
      float v=s_b6[m][col] + q[col]+q[512+col]+q[1024+col]+q[1536+col];
      s_z2[r*768+j]=fmaxf(v,0.f);
    }
    __syncthreads();                                   // B11

    // ================ P9: layer-2s (3 sequential sweeps, K=256) ================
    {
      const int uc=tid&127, r=(tid>>7)&1, kh=tid>>8;
      float a0,a1;
      a0=0.f;a1=0.f;
      {
        const u32* __restrict__ w=(const u32*)p.a2w2 + uc;
        const float* __restrict__ act=&s_z2[r*768];
        int k1=64*(kh+1);
        #pragma unroll 8
        for (int k=64*kh;k<k1;++k){ float av=act[k]; u32 u=w[(size_t)k<<7]; a0+=av*ulo(u); a1+=av*uhi(u); }
      }
      *(v2f*)&s_p[(kh*2+r)*256 + 2*uc] = (v2f){a0,a1};
      a0=0.f;a1=0.f;
      {
        const u32* __restrict__ w=(const u32*)p.g1w2 + uc;
        const float* __restrict__ act=&s_z2[r*768+256];
        int k1=64*(kh+1);
        #pragma unroll 8
        for (int k=64*kh;k<k1;++k){ float av=act[k]; u32 u=w[(size_t)k<<7]; a0+=av*ulo(u); a1+=av*uhi(u); }
      }
      *(v2f*)&s_p[2048 + (kh*2+r)*256 + 2*uc] = (v2f){a0,a1};
      a0=0.f;a1=0.f;
      {
        const u32* __restrict__ w=(const u32*)p.g2w2 + uc;
        const float* __restrict__ act=&s_z2[r*768+512];
        int k1=64*(kh+1);
        #pragma unroll 8
        for (int k=64*kh;k<k1;++k){ float av=act[k]; u32 u=w[(size_t)k<<7]; a0+=av*ulo(u); a1+=av*uhi(u); }
      }
      *(v2f*)&s_p[4096 + (kh*2+r)*256 + 2*uc] = (v2f){a0,a1};
    }
    __syncthreads();                                   // B12

    // ================ P10: mem update + x write ================
    if (tid < 512){
      int r=tid>>8, col=tid&255;
      const float* q0=s_p+r*256;
      const float* q1=s_p+2048+r*256;
      const float* q2=s_p+4096+r*256;
      float ch =s_b6[3][col] + q0[col]+q0[512+col]+q0[1024+col]+q0[1536+col];
      float gm1=s_b6[4][col] + q1[col]+q1[512+col]+q1[1024+col]+q1[1536+col];
      float gm2=s_b6[5][col] + q2[col]+q2[512+col]+q2[1024+col]+q2[1536+col];
      float mo=s_mem[r*256+col];
      s_mem[r*256+col]=sigf(gm1)*mo + sigf(gm2)*tanhf(ch);
    }
    if (t+1 < TSTEPS && tid < 818) s_x2[tid]=xp;
    __syncthreads();                                   // B13
  }

  // ================ output MLP ================
  for (int i=tid;i<1280;i+=1024){
    int r=(i>=640)?1:0, j=i-r*640;
    float v=(j<384)? s_h2[j>>7][(j&127)*2+r] : s_mem[r*256+(j-384)];
    s_last[r*640+j]=v;
  }
  __syncthreads();
  {
    const int uc=tid&127, r=(tid>>7)&1, kh=tid>>8;
    float a0=0.f,a1=0.f;
    const u32* __restrict__ w=(const u32*)p.ow1 + uc;
    const float* __restrict__ lr=&s_last[r*640];
    int k1=160*(kh+1);
    #pragma unroll 8
    for (int k=160*kh;k<k1;++k){ float av=lr[k]; u32 u=w[(size_t)k<<7]; a0+=av*ulo(u); a1+=av*uhi(u); }
    *(v2f*)&s_p[(kh*2+r)*256 + 2*uc] = (v2f){a0,a1};
  }
  __syncthreads();
  {
    float pp=0.f;
    if (tid<512){
      int r=tid>>8, col=tid&255;
      const float* q=s_p+r*256;
      float z=p.ob1[col] + q[col]+q[512+col]+q[1024+col]+q[1536+col];
      pp=fmaxf(z,0.f)*p.ow2[col];
    }
    for (int off=32; off; off>>=1) pp+=__shfl_down(pp,off);
    if (tid<512 && (tid&63)==0) s_red[tid>>6]=pp;
    __syncthreads();
    if (tid<512 && (tid&255)==0){
      int r=tid>>8;
      p.out[n0+r]=s_red[r*4]+s_red[r*4+1]+s_red[r*4+2]+s_red[r*4+3]+p.ob2[0];
    }
  }
}

extern "C" void kernel_launch(void* const* d_in, const int* in_sizes, int n_in,
                              void* d_out, int out_size, void* d_ws, size_t ws_size,
                              hipStream_t stream){
  u16* ws = (u16*)d_ws;
  struct M { int src; size_t off; int OUT, IN; };
  const M mats[15] = {
    { 5,       0, 512,  300},   // Wih_l
    { 6,  153600, 512,  128},   // Whh_l
    { 9,  219136, 512,   74},   // Wih_a
    {10,  257024, 512,  128},   // Whh_a
    {13,  322560, 512,   35},   // Wih_v
    {14,  340480, 512,  128},   // Whh_v
    {17,  406016, 256,  768},   // att1_W1
    {19,  602624, 768,  256},   // att1_W2
    {21,  799232, 256,  768},   // att2_W1
    {23,  995840, 256,  256},   // att2_W2
    {25, 1061376, 256, 1024},   // g1_W1
    {27, 1323520, 256,  256},   // g1_W2
    {29, 1389056, 256, 1024},   // g2_W1
    {31, 1651200, 256,  256},   // g2_W2
    {33, 1716736, 256,  640},   // out_W1
  };
  for (int i=0;i<15;i++){
    int total = mats[i].OUT*mats[i].IN;
    cast_transpose<<<(total+255)/256, 256, 0, stream>>>(
        (const float*)d_in[mats[i].src], ws + mats[i].off, mats[i].OUT, mats[i].IN);
  }

  P p;
  p.x     = (const float*)d_in[0];
  p.bih_l = (const float*)d_in[7];  p.bhh_l = (const float*)d_in[8];
  p.bih_a = (const float*)d_in[11]; p.bhh_a = (const float*)d_in[12];
  p.bih_v = (const float*)d_in[15]; p.bhh_v = (const float*)d_in[16];
  p.a1b1  = (const float*)d_in[18]; p.a1b2  = (const float*)d_in[20];
  p.a2b1  = (const float*)d_in[22]; p.a2b2  = (const float*)d_in[24];
  p.g1b1  = (const float*)d_in[26]; p.g1b2  = (const float*)d_in[28];
  p.g2b1  = (const float*)d_in[30]; p.g2b2  = (const float*)d_in[32];
  p.ob1   = (const float*)d_in[34]; p.ow2   = (const float*)d_in[35];
  p.ob2   = (const float*)d_in[36];
  p.ihl   = ws + 0;       p.hhl  = ws + 153600;
  p.iha   = ws + 219136;  p.hha  = ws + 257024;
  p.ihv   = ws + 322560;  p.hhv  = ws + 340480;
  p.a1w1  = ws + 406016;  p.a1w2 = ws + 602624;
  p.a2w1  = ws + 799232;  p.a2w2 = ws + 995840;
  p.g1w1  = ws + 1061376; p.g1w2 = ws + 1323520;
  p.g2w1  = ws + 1389056; p.g2w2 = ws + 1651200;
  p.ow1   = ws + 1716736;
  p.out   = (float*)d_out;

  mfn_persistent<<<NBATCH/2, 1024, 0, stream>>>(p);
}

// Round 7
// 47203.915 us; speedup vs baseline: 3.6021x; 3.6021x over previous
//
#include <hip/hip_runtime.h>
#include <math.h>

#define TSTEPS 512
#define NBATCH 256
#define DLL 300
#define DAA 74
#define DVV 35
#define DX  409
#define DH  128
#define DMEM 256
#define CST 768   // 6*DH

typedef unsigned short u16;
typedef unsigned int   u32;
typedef float v2f __attribute__((ext_vector_type(2)));

__device__ __forceinline__ float ulo(u32 u){ return __uint_as_float(u<<16); }
__device__ __forceinline__ float uhi(u32 u){ return __uint_as_float(u & 0xffff0000u); }
__device__ __forceinline__ float sigf(float x){ return 1.0f/(1.0f+expf(-x)); }

// dst[k*OUT + o] = bf16(src[o*IN + k])
__global__ void cast_transpose(const float* __restrict__ src, u16* __restrict__ dst,
                               int OUT, int IN){
  int idx = blockIdx.x*blockDim.x + threadIdx.x;
  int total = OUT*IN;
  if (idx >= total) return;
  int k = idx / OUT;
  int o = idx - k*OUT;
  float v = src[o*IN + k];
  u32 u = __float_as_uint(v);
  u32 r = (u + 0x7fffu + ((u>>16)&1u)) >> 16;   // RNE
  dst[idx] = (u16)r;
}

struct P {
  const float* x;
  const float *bih_l,*bhh_l,*bih_a,*bhh_a,*bih_v,*bhh_v;
  const float *a1b1,*a1b2,*a2b1,*a2b2,*g1b1,*g1b2,*g2b1,*g2b2;
  const float *ob1,*ow2,*ob2;
  const u16 *ihl,*hhl,*iha,*hha,*ihv,*hhv;
  const u16 *a1w1,*a1w2,*a2w1,*a2w2,*g1w1,*g1w2,*g2w1,*g2w2,*ow1;
  float* out;
};

// 128 blocks x 512 threads, 2 rows/block. Coherent per-matrix sweeps, K-split <= 2.
// u32 loads: 2 cols/load; rows share the load where occupancy allows (4 MAC/load),
// else r-dup (each row's thread re-loads the same u32; +1.8MB/block-step L2).
__global__ void __launch_bounds__(512, 4)
mfn_persistent(P p){
  __shared__ __align__(16) float s_x2[820];      // [feat*2+r]
  __shared__ __align__(16) float s_h2[3][256];   // [m][u*2+r]
  __shared__ __align__(16) float s_c2[3][256];
  __shared__ __align__(16) float s_cstar[1536];  // [idx*2+r]
  __shared__ __align__(16) float s_z[512];       // [col*2+r]
  __shared__ __align__(16) float s_attm[2048];   // [idx*2+r], idx<1024 (att768|mem256)
  __shared__ __align__(16) float s_z2[1536];     // [(mat*256+col)*2+r]
  __shared__ __align__(16) float s_mem[512];     // [r*256+col]
  __shared__ __align__(16) float s_p[7168];      // partials / scores (phase-local)
  __shared__ __align__(16) float s_last[1280];   // [j*2+r]
  __shared__ __align__(16) float s_bl[3][512];
  __shared__ __align__(16) float s_a1b1[256];
  __shared__ __align__(16) float s_a1b2[768];
  __shared__ __align__(16) float s_b6[6][256];   // a2b1,g1b1,g2b1,a2b2,g1b2,g2b2
  __shared__ float s_red[16];

  const int tid = threadIdx.x;
  const int n0  = blockIdx.x*2;

  // ---- init ----
  s_bl[0][tid]=p.bih_l[tid]+p.bhh_l[tid];
  s_bl[1][tid]=p.bih_a[tid]+p.bhh_a[tid];
  s_bl[2][tid]=p.bih_v[tid]+p.bhh_v[tid];
  s_mem[tid]=0.f;
  if (tid < 256){
    s_a1b1[tid]=p.a1b1[tid];
    s_b6[0][tid]=p.a2b1[tid]; s_b6[1][tid]=p.g1b1[tid]; s_b6[2][tid]=p.g2b1[tid];
    s_b6[3][tid]=p.a2b2[tid]; s_b6[4][tid]=p.g1b2[tid]; s_b6[5][tid]=p.g2b2[tid];
  }
  for (int i=tid;i<768;i+=512){
    s_a1b2[i]=p.a1b2[i];
    (&s_h2[0][0])[i]=0.f; (&s_c2[0][0])[i]=0.f;
  }
  for (int i=tid;i<818;i+=512)
    s_x2[i]=p.x[(size_t)(n0+(i&1))*DX + (i>>1)];
  __syncthreads();

  for (int t=0; t<TSTEPS; t++){
    // ======== P1: LSTM gates. pc=tid&255 col-pair of OUT=512, kh=tid>>8 K-half ========
    {
      const int pc=tid&255, kh=tid>>8;
      float a00,a01,a10,a11;
      // L: x[0,300) split 150/150, h split 64/64
      a00=0.f;a01=0.f;a10=0.f;a11=0.f;
      {
        const u32* __restrict__ wp=(const u32*)p.ihl + (size_t)(150*kh)*256 + pc;
        #pragma unroll 4
        for (int k=150*kh,ke=150*(kh+1);k<ke;++k){
          v2f xv=*(const v2f*)&s_x2[k*2];
          u32 u=*wp; wp+=256;
          float w0=ulo(u),w1=uhi(u);
          a00+=xv.x*w0; a01+=xv.x*w1; a10+=xv.y*w0; a11+=xv.y*w1;
        }
        const u32* __restrict__ hp=(const u32*)p.hhl + (size_t)(64*kh)*256 + pc;
        #pragma unroll 4
        for (int k=64*kh,ke=64*(kh+1);k<ke;++k){
          v2f hv=*(const v2f*)&s_h2[0][k*2];
          u32 u=*hp; hp+=256;
          float w0=ulo(u),w1=uhi(u);
          a00+=hv.x*w0; a01+=hv.x*w1; a10+=hv.y*w0; a11+=hv.y*w1;
        }
      }
      *(v2f*)&s_p[kh*1024 + 2*pc]       = (v2f){a00,a01};
      *(v2f*)&s_p[kh*1024 + 512 + 2*pc] = (v2f){a10,a11};
      // A: x 37/37, h 64/64
      a00=0.f;a01=0.f;a10=0.f;a11=0.f;
      {
        const u32* __restrict__ wp=(const u32*)p.iha + (size_t)(37*kh)*256 + pc;
        #pragma unroll 4
        for (int k=37*kh,ke=37*(kh+1);k<ke;++k){
          v2f xv=*(const v2f*)&s_x2[(DLL+k)*2];
          u32 u=*wp; wp+=256;
          float w0=ulo(u),w1=uhi(u);
          a00+=xv.x*w0; a01+=xv.x*w1; a10+=xv.y*w0; a11+=xv.y*w1;
        }
        const u32* __restrict__ hp=(const u32*)p.hha + (size_t)(64*kh)*256 + pc;
        #pragma unroll 4
        for (int k=64*kh,ke=64*(kh+1);k<ke;++k){
          v2f hv=*(const v2f*)&s_h2[1][k*2];
          u32 u=*hp; hp+=256;
          float w0=ulo(u),w1=uhi(u);
          a00+=hv.x*w0; a01+=hv.x*w1; a10+=hv.y*w0; a11+=hv.y*w1;
        }
      }
      *(v2f*)&s_p[2048 + kh*1024 + 2*pc]       = (v2f){a00,a01};
      *(v2f*)&s_p[2048 + kh*1024 + 512 + 2*pc] = (v2f){a10,a11};
      // V: x 18/17, h 64/64
      a00=0.f;a01=0.f;a10=0.f;a11=0.f;
      {
        int ks=kh?18:0, ke=kh?35:18;
        const u32* __restrict__ wp=(const u32*)p.ihv + (size_t)ks*256 + pc;
        #pragma unroll 4
        for (int k=ks;k<ke;++k){
          v2f xv=*(const v2f*)&s_x2[(DLL+DAA+k)*2];
          u32 u=*wp; wp+=256;
          float w0=ulo(u),w1=uhi(u);
          a00+=xv.x*w0; a01+=xv.x*w1; a10+=xv.y*w0; a11+=xv.y*w1;
        }
        const u32* __restrict__ hp=(const u32*)p.hhv + (size_t)(64*kh)*256 + pc;
        #pragma unroll 4
        for (int k=64*kh,ke2=64*(kh+1);k<ke2;++k){
          v2f hv=*(const v2f*)&s_h2[2][k*2];
          u32 u=*hp; hp+=256;
          float w0=ulo(u),w1=uhi(u);
          a00+=hv.x*w0; a01+=hv.x*w1; a10+=hv.y*w0; a11+=hv.y*w1;
        }
      }
      *(v2f*)&s_p[4096 + kh*1024 + 2*pc]       = (v2f){a00,a01};
      *(v2f*)&s_p[4096 + kh*1024 + 512 + 2*pc] = (v2f){a10,a11};
    }
    __syncthreads();                               // B1

    // ======== P2: LSTM activations (768 tasks) ========
    for (int task=tid; task<768; task+=512){
      int m=task>>8, rem=task&255, u=rem>>1, r=rem&1;
      const float* pm = s_p + m*2048;
      const float* bl = s_bl[m];
      float g0 = bl[u]     + pm[r*512+u]     + pm[1024+r*512+u];
      float g1 = bl[128+u] + pm[r*512+128+u] + pm[1024+r*512+128+u];
      float g2 = bl[256+u] + pm[r*512+256+u] + pm[1024+r*512+256+u];
      float g3 = bl[384+u] + pm[r*512+384+u] + pm[1024+r*512+384+u];
      float ig=sigf(g0), fg=sigf(g1), gg=tanhf(g2), og=sigf(g3);
      float co=s_c2[m][u*2+r];
      float c = fg*co + ig*gg;
      float h = og*tanhf(c);
      s_c2[m][u*2+r]=c; s_h2[m][u*2+r]=h;
      s_cstar[(m*128+u)*2+r]     = co;
      s_cstar[(384+m*128+u)*2+r] = c;
    }
    __syncthreads();                               // B2

    // ======== P3: att1_W1 (K=768, OUT=256); r-dup, kh2 ========
    {
      const int pc=tid&127, kh=(tid>>7)&1, r=tid>>8;
      float a0=0.f,a1=0.f;
      const u32* __restrict__ wp=(const u32*)p.a1w1 + (size_t)(384*kh)*128 + pc;
      #pragma unroll 4
      for (int k=384*kh,ke=384*(kh+1);k<ke;++k){
        float a=s_cstar[k*2+r];
        u32 u=*wp; wp+=128;
        a0+=a*ulo(u); a1+=a*uhi(u);
      }
      *(v2f*)&s_p[kh*512 + r*256 + 2*pc] = (v2f){a0,a1};
    }
    __syncthreads();                               // B3

    // ======== P4: z1 finalize ========
    {
      int r=tid>>8, col=tid&255;
      float z = s_a1b1[col] + s_p[r*256+col] + s_p[512+r*256+col];
      s_z[col*2+r] = fmaxf(z,0.f);
    }
    __syncthreads();                               // B4

    // ======== P5: att1_W2 (K=256, OUT=768); tid<384 busy; idle threads prefetch x ======
    if (tid < 384){
      const int pc=tid&127, ms=tid>>7;
      float a00=0.f,a01=0.f,a10=0.f,a11=0.f;
      const u32* __restrict__ wp=(const u32*)p.a1w2 + ms*128 + pc;
      #pragma unroll 4
      for (int k=0;k<256;++k){
        v2f a=*(const v2f*)&s_z[k*2];
        u32 u=*wp; wp+=384;
        float w0=ulo(u),w1=uhi(u);
        a00+=a.x*w0; a01+=a.x*w1; a10+=a.y*w0; a11+=a.y*w1;
      }
      *(v2f*)&s_p[ms*256 + 2*pc]       = (v2f){a00,a01};
      *(v2f*)&s_p[768 + ms*256 + 2*pc] = (v2f){a10,a11};
    } else if (t+1 < TSTEPS){
      const float* __restrict__ xb = p.x + (size_t)(t+1)*NBATCH*DX;
      int i0 = tid-384;
      #pragma unroll
      for (int j=0;j<7;j++){
        int i = i0 + j*128;
        if (i < 818) s_x2[i] = xb[(size_t)(n0+(i&1))*DX + (i>>1)];
      }
    }
    __syncthreads();                               // B5

    // ======== softmax + attended ========
    {
      int r=tid>>8, col=tid&255;
      const float* q = s_p + r*768;
      float s0=s_a1b2[col]+q[col], s1=s_a1b2[256+col]+q[256+col], s2=s_a1b2[512+col]+q[512+col];
      float mx=fmaxf(fmaxf(s0,s1),s2);
      for (int off=32; off; off>>=1) mx=fmaxf(mx,__shfl_down(mx,off));
      if ((tid&63)==0) s_red[tid>>6]=mx;
      __syncthreads();                             // B6
      float m = fmaxf(fmaxf(s_red[r*4],s_red[r*4+1]),fmaxf(s_red[r*4+2],s_red[r*4+3]));
      float e0=expf(s0-m), e1=expf(s1-m), e2=expf(s2-m);
      float ss=e0+e1+e2;
      for (int off=32; off; off>>=1) ss+=__shfl_down(ss,off);
      if ((tid&63)==0) s_red[8+(tid>>6)]=ss;
      s_attm[(768+col)*2+r] = s_mem[r*256+col];
      __syncthreads();                             // B7
      float inv=1.f/(s_red[8+r*4]+s_red[8+r*4+1]+s_red[8+r*4+2]+s_red[8+r*4+3]);
      s_attm[col*2+r]       = e0*inv*s_cstar[col*2+r];
      s_attm[(256+col)*2+r] = e1*inv*s_cstar[(256+col)*2+r];
      s_attm[(512+col)*2+r] = e2*inv*s_cstar[(512+col)*2+r];
    }
    __syncthreads();                               // B8

    // ======== P7: a2w1/g1w1/g2w1 (OUT=256); r-dup, kh2 ========
    {
      const int pc=tid&127, kh=(tid>>7)&1, r=tid>>8;
      float a0,a1;
      // a2w1 K=768
      a0=0.f;a1=0.f;
      {
        const u32* __restrict__ wp=(const u32*)p.a2w1 + (size_t)(384*kh)*128 + pc;
        #pragma unroll 4
        for (int k=384*kh,ke=384*(kh+1);k<ke;++k){
          float a=s_attm[k*2+r];
          u32 u=*wp; wp+=128;
          a0+=a*ulo(u); a1+=a*uhi(u);
        }
      }
      *(v2f*)&s_p[kh*512 + r*256 + 2*pc] = (v2f){a0,a1};
      // g1w1 K=1024
      a0=0.f;a1=0.f;
      {
        const u32* __restrict__ wp=(const u32*)p.g1w1 + (size_t)(512*kh)*128 + pc;
        #pragma unroll 4
        for (int k=512*kh,ke=512*(kh+1);k<ke;++k){
          float a=s_attm[k*2+r];
          u32 u=*wp; wp+=128;
          a0+=a*ulo(u); a1+=a*uhi(u);
        }
      }
      *(v2f*)&s_p[1024 + kh*512 + r*256 + 2*pc] = (v2f){a0,a1};
      // g2w1 K=1024
      a0=0.f;a1=0.f;
      {
        const u32* __restrict__ wp=(const u32*)p.g2w1 + (size_t)(512*kh)*128 + pc;
        #pragma unroll 4
        for (int k=512*kh,ke=512*(kh+1);k<ke;++k){
          float a=s_attm[k*2+r];
          u32 u=*wp; wp+=128;
          a0+=a*ulo(u); a1+=a*uhi(u);
        }
      }
      *(v2f*)&s_p[2048 + kh*512 + r*256 + 2*pc] = (v2f){a0,a1};
    }
    __syncthreads();                               // B9

    // ======== P8: z2 finalize (1536 tasks) ========
    for (int i=tid;i<1536;i+=512){
      int mat=i>>9, rem=i&511, r=rem>>8, col=rem&255;
      float v = s_b6[mat][col] + s_p[mat*1024 + r*256+col] + s_p[mat*1024+512 + r*256+col];
      s_z2[(mat*256+col)*2+r] = fmaxf(v,0.f);
    }
    __syncthreads();                               // B10

    // ======== P9: a2w2/g1w2/g2w2 (K=256, OUT=256); tid<384, full K, direct out ======
    if (tid < 384){
      const int pc=tid&127, mat=tid>>7;
      const u16* W = (mat==0)? p.a2w2 : ((mat==1)? p.g1w2 : p.g2w2);
      const float* __restrict__ act = &s_z2[mat*512];
      float a00=0.f,a01=0.f,a10=0.f,a11=0.f;
      const u32* __restrict__ wp=(const u32*)W + pc;
      #pragma unroll 4
      for (int k=0;k<256;++k){
        v2f a=*(const v2f*)&act[k*2];
        u32 u=*wp; wp+=128;
        float w0=ulo(u),w1=uhi(u);
        a00+=a.x*w0; a01+=a.x*w1; a10+=a.y*w0; a11+=a.y*w1;
      }
      *(v2f*)&s_p[mat*512 + 2*pc]       = (v2f){a00,a01};
      *(v2f*)&s_p[mat*512 + 256 + 2*pc] = (v2f){a10,a11};
    }
    __syncthreads();                               // B11

    // ======== P10: mem update ========
    {
      int r=tid>>8, col=tid&255;
      float ch  = s_b6[3][col] + s_p[r*256+col];
      float gm1 = s_b6[4][col] + s_p[512 + r*256+col];
      float gm2 = s_b6[5][col] + s_p[1024 + r*256+col];
      float mo = s_mem[r*256+col];
      s_mem[r*256+col] = sigf(gm1)*mo + sigf(gm2)*tanhf(ch);
    }
    __syncthreads();                               // B12
  }

  // ======== output MLP ========
  for (int i=tid;i<1280;i+=512){
    int j=i>>1, r=i&1;
    float v = (j<384)? s_h2[j>>7][(j&127)*2+r] : s_mem[r*256 + (j-384)];
    s_last[i]=v;
  }
  __syncthreads();
  if (tid < 256){
    const int pc=tid&127, kh=tid>>7;
    float a00=0.f,a01=0.f,a10=0.f,a11=0.f;
    const u32* __restrict__ wp=(const u32*)p.ow1 + (size_t)(320*kh)*128 + pc;
    #pragma unroll 4
    for (int k=320*kh,ke=320*(kh+1);k<ke;++k){
      v2f a=*(const v2f*)&s_last[k*2];
      u32 u=*wp; wp+=128;
      float w0=ulo(u),w1=uhi(u);
      a00+=a.x*w0; a01+=a.x*w1; a10+=a.y*w0; a11+=a.y*w1;
    }
    *(v2f*)&s_p[kh*512 + 2*pc]       = (v2f){a00,a01};
    *(v2f*)&s_p[kh*512 + 256 + 2*pc] = (v2f){a10,a11};
  }
  __syncthreads();
  {
    int r=tid>>8, col=tid&255;
    float z = p.ob1[col] + s_p[r*256+col] + s_p[512+r*256+col];
    float pp = fmaxf(z,0.f)*p.ow2[col];
    for (int off=32; off; off>>=1) pp+=__shfl_down(pp,off);
    if ((tid&63)==0) s_red[tid>>6]=pp;
    __syncthreads();
    if (tid==0)   p.out[n0]   = s_red[0]+s_red[1]+s_red[2]+s_red[3]+p.ob2[0];
    if (tid==256) p.out[n0+1] = s_red[4]+s_red[5]+s_red[6]+s_red[7]+p.ob2[0];
  }
}

extern "C" void kernel_launch(void* const* d_in, const int* in_sizes, int n_in,
                              void* d_out, int out_size, void* d_ws, size_t ws_size,
                              hipStream_t stream){
  u16* ws = (u16*)d_ws;
  struct M { int src; size_t off; int OUT, IN; };
  const M mats[15] = {
    { 5,       0, 512,  300},   // Wih_l
    { 6,  153600, 512,  128},   // Whh_l
    { 9,  219136, 512,   74},   // Wih_a
    {10,  257024, 512,  128},   // Whh_a
    {13,  322560, 512,   35},   // Wih_v
    {14,  340480, 512,  128},   // Whh_v
    {17,  406016, 256,  768},   // att1_W1
    {19,  602624, 768,  256},   // att1_W2
    {21,  799232, 256,  768},   // att2_W1
    {23,  995840, 256,  256},   // att2_W2
    {25, 1061376, 256, 1024},   // g1_W1
    {27, 1323520, 256,  256},   // g1_W2
    {29, 1389056, 256, 1024},   // g2_W1
    {31, 1651200, 256,  256},   // g2_W2
    {33, 1716736, 256,  640},   // out_W1
  };
  for (int i=0;i<15;i++){
    int total = mats[i].OUT*mats[i].IN;
    cast_transpose<<<(total+255)/256, 256, 0, stream>>>(
        (const float*)d_in[mats[i].src], ws + mats[i].off, mats[i].OUT, mats[i].IN);
  }

  P p;
  p.x     = (const float*)d_in[0];
  p.bih_l = (const float*)d_in[7];  p.bhh_l = (const float*)d_in[8];
  p.bih_a = (const float*)d_in[11]; p.bhh_a = (const float*)d_in[12];
  p.bih_v = (const float*)d_in[15]; p.bhh_v = (const float*)d_in[16];
  p.a1b1  = (const float*)d_in[18]; p.a1b2  = (const float*)d_in[20];
  p.a2b1  = (const float*)d_in[22]; p.a2b2  = (const float*)d_in[24];
  p.g1b1  = (const float*)d_in[26]; p.g1b2  = (const float*)d_in[28];
  p.g2b1  = (const float*)d_in[30]; p.g2b2  = (const float*)d_in[32];
  p.ob1   = (const float*)d_in[34]; p.ow2   = (const float*)d_in[35];
  p.ob2   = (const float*)d_in[36];
  p.ihl   = ws + 0;       p.hhl  = ws + 153600;
  p.iha   = ws + 219136;  p.hha  = ws + 257024;
  p.ihv   = ws + 322560;  p.hhv  = ws + 340480;
  p.a1w1  = ws + 406016;  p.a1w2 = ws + 602624;
  p.a2w1  = ws + 799232;  p.a2w2 = ws + 995840;
  p.g1w1  = ws + 1061376; p.g1w2 = ws + 1323520;
  p.g2w1  = ws + 1389056; p.g2w2 = ws + 1651200;
  p.ow1   = ws + 1716736;
  p.out   = (float*)d_out;

  mfn_persistent<<<NBATCH/2, 512, 0, stream>>>(p);
}

// Round 8
// 39353.427 us; speedup vs baseline: 4.3207x; 1.1995x over previous
//
#include <hip/hip_runtime.h>
#include <math.h>

#define TSTEPS 512
#define NBATCH 256
#define DLL 300
#define DAA 74
#define DVV 35
#define DX  409
#define DH  128
#define DMEM 256
#define CST 768   // 6*DH

typedef unsigned short u16;
typedef unsigned int   u32;
typedef float v2f __attribute__((ext_vector_type(2)));

__device__ __forceinline__ float ulo(u32 u){ return __uint_as_float(u<<16); }
__device__ __forceinline__ float uhi(u32 u){ return __uint_as_float(u & 0xffff0000u); }
__device__ __forceinline__ float sigf(float x){ return 1.0f/(1.0f+expf(-x)); }

// 8k-tiled: dst[(kb*OUT + o)*8 + j] = bf16(src[o*IN + kb*8+j]) or 0 pad
__global__ void cast_tile8(const float* __restrict__ src, u16* __restrict__ dst,
                           int OUT, int IN, int INP){
  int e = blockIdx.x*blockDim.x + threadIdx.x;
  if (e >= OUT*INP) return;
  int j = e & 7;
  int q = e >> 3;
  int o = q % OUT;
  int kb = q / OUT;
  int k = kb*8 + j;
  float v = (k < IN) ? src[o*IN + k] : 0.f;
  u32 u = __float_as_uint(v);
  u32 r = (u + 0x7fffu + ((u>>16)&1u)) >> 16;   // RNE
  dst[e] = (u16)r;
}

struct P {
  const float* x;
  const float *bih_l,*bhh_l,*bih_a,*bhh_a,*bih_v,*bhh_v;
  const float *a1b1,*a1b2,*a2b1,*a2b2,*g1b1,*g1b2,*g2b1,*g2b2;
  const float *ob1,*ow2,*ob2;
  const u16 *ihl,*hhl,*iha,*hha,*ihv,*hhv;
  const u16 *a1w1,*a1w2,*a2w1,*a2w2,*g1w1,*g1w2,*g2w1,*g2w2,*ow1;
  float* out;
};

// one 8k tile: 8 bf16 weights (one col) x acts[16] (8k x 2 rows) -> 2 row-accs
__device__ __forceinline__ void kb16(const uint4* __restrict__ wp,
                                     const float* __restrict__ ap,
                                     float &a0, float &a1){
  uint4 w = *wp;
  float4 x0=*(const float4*)ap, x1=*(const float4*)(ap+4),
         x2=*(const float4*)(ap+8), x3=*(const float4*)(ap+12);
  a0 += x0.x*ulo(w.x); a1 += x0.y*ulo(w.x);
  a0 += x0.z*uhi(w.x); a1 += x0.w*uhi(w.x);
  a0 += x1.x*ulo(w.y); a1 += x1.y*ulo(w.y);
  a0 += x1.z*uhi(w.y); a1 += x1.w*uhi(w.y);
  a0 += x2.x*ulo(w.z); a1 += x2.y*ulo(w.z);
  a0 += x2.z*uhi(w.z); a1 += x2.w*uhi(w.z);
  a0 += x3.x*ulo(w.w); a1 += x3.y*ulo(w.w);
  a0 += x3.z*uhi(w.w); a1 += x3.w*uhi(w.w);
}

// padded x index -> feature index (or -1 for pad)
__device__ __forceinline__ int xfeat(int i){
  if (i < 300) return i;
  if (i < 304) return -1;
  if (i < 378) return i-4;
  if (i < 384) return -1;
  if (i < 419) return i-10;
  return -1;
}

__global__ void __launch_bounds__(512, 2)
mfn_persistent(P p){
  __shared__ __align__(16) float s_x2[848];      // [i*2+r], i<424 padded (pads stay 0)
  __shared__ __align__(16) float s_h2[3][256];   // [m][u*2+r]
  __shared__ __align__(16) float s_c2[3][256];
  __shared__ __align__(16) float s_cstar[1536];  // [idx*2+r]
  __shared__ __align__(16) float s_z[512];       // [k*2+r]
  __shared__ __align__(16) float s_attm[2048];   // [idx*2+r], idx<1024 (att768|mem256)
  __shared__ __align__(16) float s_z2[1536];     // [(mat*256+col)*2+r]
  __shared__ __align__(16) float s_mem[512];     // [r*256+col]
  __shared__ __align__(16) float s_p[3072];      // gates / partials
  __shared__ __align__(16) float s_last[1280];   // [j*2+r]
  __shared__ __align__(16) float s_a1b1[256];
  __shared__ __align__(16) float s_a1b2[768];
  __shared__ __align__(16) float s_b6[6][256];   // a2b1,g1b1,g2b1,a2b2,g1b2,g2b2
  __shared__ float s_red[16];

  const int tid = threadIdx.x;
  const int n0  = blockIdx.x*2;
  const int col = tid&255, rr = tid>>8, kh = tid>>8;

  // LSTM biases in registers (1 col/thread in P1)
  const float bLg = p.bih_l[tid]+p.bhh_l[tid];
  const float bAg = p.bih_a[tid]+p.bhh_a[tid];
  const float bVg = p.bih_v[tid]+p.bhh_v[tid];

  // ---- init ----
  if (tid < 256){
    s_a1b1[tid]=p.a1b1[tid];
    s_b6[0][tid]=p.a2b1[tid]; s_b6[1][tid]=p.g1b1[tid]; s_b6[2][tid]=p.g2b1[tid];
    s_b6[3][tid]=p.a2b2[tid]; s_b6[4][tid]=p.g1b2[tid]; s_b6[5][tid]=p.g2b2[tid];
  }
  for (int i=tid;i<768;i+=512){
    s_a1b2[i]=p.a1b2[i];
    (&s_h2[0][0])[i]=0.f; (&s_c2[0][0])[i]=0.f;
  }
  s_mem[tid]=0.f;
  for (int i2=tid;i2<848;i2+=512){
    float v=0.f; int f=xfeat(i2>>1);
    if (f>=0) v = p.x[(size_t)(n0+(i2&1))*DX + f];
    s_x2[i2]=v;
  }
  __syncthreads();

  for (int t=0; t<TSTEPS; t++){
    // ================ P1: LSTM gates (1 col/thread, coherent full-K sweeps) ========
    {
      float a0,a1;
      // L
      a0=0.f; a1=0.f;
      {
        const uint4* __restrict__ wp=(const uint4*)p.ihl + tid;
        #pragma unroll 4
        for (int kb=0;kb<38;++kb){ kb16(wp,&s_x2[kb*16],a0,a1); wp+=512; }
        const uint4* __restrict__ hp=(const uint4*)p.hhl + tid;
        #pragma unroll 4
        for (int kb=0;kb<16;++kb){ kb16(hp,&s_h2[0][kb*16],a0,a1); hp+=512; }
      }
      *(v2f*)&s_p[tid*2] = (v2f){a0+bLg, a1+bLg};
      // A
      a0=0.f; a1=0.f;
      {
        const uint4* __restrict__ wp=(const uint4*)p.iha + tid;
        #pragma unroll 4
        for (int kb=0;kb<10;++kb){ kb16(wp,&s_x2[608+kb*16],a0,a1); wp+=512; }
        const uint4* __restrict__ hp=(const uint4*)p.hha + tid;
        #pragma unroll 4
        for (int kb=0;kb<16;++kb){ kb16(hp,&s_h2[1][kb*16],a0,a1); hp+=512; }
      }
      *(v2f*)&s_p[1024 + tid*2] = (v2f){a0+bAg, a1+bAg};
      // V
      a0=0.f; a1=0.f;
      {
        const uint4* __restrict__ wp=(const uint4*)p.ihv + tid;
        #pragma unroll 4
        for (int kb=0;kb<5;++kb){ kb16(wp,&s_x2[768+kb*16],a0,a1); wp+=512; }
        const uint4* __restrict__ hp=(const uint4*)p.hhv + tid;
        #pragma unroll 4
        for (int kb=0;kb<16;++kb){ kb16(hp,&s_h2[2][kb*16],a0,a1); hp+=512; }
      }
      *(v2f*)&s_p[2048 + tid*2] = (v2f){a0+bVg, a1+bVg};
    }
    __syncthreads();                               // B1

    // ================ P2: LSTM activations (768 tasks) ================
    for (int task=tid; task<768; task+=512){
      int m=task>>8, rem=task&255, u=rem>>1, r=rem&1;
      const float* pm = s_p + m*1024;
      float g0 = pm[u*2+r];
      float g1 = pm[(128+u)*2+r];
      float g2 = pm[(256+u)*2+r];
      float g3 = pm[(384+u)*2+r];
      float ig=sigf(g0), fg=sigf(g1), gg=tanhf(g2), og=sigf(g3);
      float co=s_c2[m][u*2+r];
      float c = fg*co + ig*gg;
      float h = og*tanhf(c);
      s_c2[m][u*2+r]=c; s_h2[m][u*2+r]=h;
      s_cstar[(m*128+u)*2+r]     = co;
      s_cstar[(384+m*128+u)*2+r] = c;
    }
    __syncthreads();                               // B2

    // ================ P3: att1_W1 (K=768, OUT=256, 2-way kh split) ================
    {
      float a0=0.f,a1=0.f;
      const uint4* __restrict__ wp=(const uint4*)p.a1w1 + (kh*48*256 + col);
      const float* __restrict__ base=&s_cstar[kh*48*16];
      #pragma unroll 4
      for (int kb=0;kb<48;++kb){ kb16(wp,base+kb*16,a0,a1); wp+=256; }
      *(v2f*)&s_p[kh*512 + col*2] = (v2f){a0,a1};
    }
    __syncthreads();                               // B3

    // ================ P4: z1 finalize ================
    {
      float z = s_a1b1[col] + s_p[col*2+rr] + s_p[512+col*2+rr];
      s_z[col*2+rr] = fmaxf(z,0.f);
    }
    __syncthreads();                               // B4

    // ================ P5: att1_W2 (K=256, OUT=768; 3 cols/thread share acts) ========
    {
      float a0=0.f,a1=0.f,b0=0.f,b1=0.f,c0=0.f,c1=0.f;
      const uint4* __restrict__ w0=(const uint4*)p.a1w2 + (kh*16*768 + col);
      const uint4* __restrict__ w1=w0+256;
      const uint4* __restrict__ w2=w0+512;
      const float* __restrict__ base=&s_z[kh*16*16];
      #pragma unroll 2
      for (int kb=0;kb<16;++kb){
        const float* ap = base + kb*16;
        kb16(w0,ap,a0,a1); w0+=768;
        kb16(w1,ap,b0,b1); w1+=768;
        kb16(w2,ap,c0,c1); w2+=768;
      }
      *(v2f*)&s_p[kh*1536 + col*2]         = (v2f){a0,a1};
      *(v2f*)&s_p[kh*1536 + (256+col)*2]   = (v2f){b0,b1};
      *(v2f*)&s_p[kh*1536 + (512+col)*2]   = (v2f){c0,c1};
    }
    __syncthreads();                               // B5

    // ================ softmax + attended ================
    {
      float s0 = s_a1b2[col]     + s_p[col*2+rr]       + s_p[1536+col*2+rr];
      float s1 = s_a1b2[256+col] + s_p[(256+col)*2+rr] + s_p[1536+(256+col)*2+rr];
      float s2 = s_a1b2[512+col] + s_p[(512+col)*2+rr] + s_p[1536+(512+col)*2+rr];
      float mx=fmaxf(fmaxf(s0,s1),s2);
      for (int off=32; off; off>>=1) mx=fmaxf(mx,__shfl_down(mx,off));
      if ((tid&63)==0) s_red[tid>>6]=mx;
      __syncthreads();                             // B6
      float m = fmaxf(fmaxf(s_red[rr*4],s_red[rr*4+1]),fmaxf(s_red[rr*4+2],s_red[rr*4+3]));
      float e0=expf(s0-m), e1=expf(s1-m), e2=expf(s2-m);
      float ss=e0+e1+e2;
      for (int off=32; off; off>>=1) ss+=__shfl_down(ss,off);
      if ((tid&63)==0) s_red[8+(tid>>6)]=ss;
      s_attm[(768+col)*2+rr] = s_mem[rr*256+col];
      __syncthreads();                             // B7
      float inv=1.f/(s_red[8+rr*4]+s_red[8+rr*4+1]+s_red[8+rr*4+2]+s_red[8+rr*4+3]);
      s_attm[col*2+rr]       = e0*inv*s_cstar[col*2+rr];
      s_attm[(256+col)*2+rr] = e1*inv*s_cstar[(256+col)*2+rr];
      s_attm[(512+col)*2+rr] = e2*inv*s_cstar[(512+col)*2+rr];
    }
    __syncthreads();                               // B8

    // ================ P7: a2w1 (K=768) / g1w1,g2w1 (K=1024), 2-way kh ================
    {
      float a0,a1;
      a0=0.f;a1=0.f;
      {
        const uint4* __restrict__ wp=(const uint4*)p.a2w1 + (kh*48*256 + col);
        const float* __restrict__ base=&s_attm[kh*48*16];
        #pragma unroll 4
        for (int kb=0;kb<48;++kb){ kb16(wp,base+kb*16,a0,a1); wp+=256; }
      }
      *(v2f*)&s_p[kh*512 + col*2] = (v2f){a0,a1};
      a0=0.f;a1=0.f;
      {
        const uint4* __restrict__ wp=(const uint4*)p.g1w1 + (kh*64*256 + col);
        const float* __restrict__ base=&s_attm[kh*64*16];
        #pragma unroll 4
        for (int kb=0;kb<64;++kb){ kb16(wp,base+kb*16,a0,a1); wp+=256; }
      }
      *(v2f*)&s_p[1024 + kh*512 + col*2] = (v2f){a0,a1};
      a0=0.f;a1=0.f;
      {
        const uint4* __restrict__ wp=(const uint4*)p.g2w1 + (kh*64*256 + col);
        const float* __restrict__ base=&s_attm[kh*64*16];
        #pragma unroll 4
        for (int kb=0;kb<64;++kb){ kb16(wp,base+kb*16,a0,a1); wp+=256; }
      }
      *(v2f*)&s_p[2048 + kh*512 + col*2] = (v2f){a0,a1};
    }
    __syncthreads();                               // B9

    // ================ P8: z2 finalize (1536 tasks) ================
    for (int i=tid;i<1536;i+=512){
      int mat=i>>9, rem=i&511, c2=rem>>1, r=rem&1;
      const float* q = s_p + mat*1024;
      float v = s_b6[mat][c2] + q[c2*2+r] + q[512+c2*2+r];
      s_z2[(mat*256+c2)*2+r] = fmaxf(v,0.f);
    }
    __syncthreads();                               // B10

    // ================ P9: a2w2/g1w2/g2w2 (K=256 each, 2-way kh) ================
    {
      float a0,a1;
      a0=0.f;a1=0.f;
      {
        const uint4* __restrict__ wp=(const uint4*)p.a2w2 + (kh*16*256 + col);
        const float* __restrict__ base=&s_z2[kh*16*16];
        #pragma unroll 4
        for (int kb=0;kb<16;++kb){ kb16(wp,base+kb*16,a0,a1); wp+=256; }
      }
      *(v2f*)&s_p[kh*512 + col*2] = (v2f){a0,a1};
      a0=0.f;a1=0.f;
      {
        const uint4* __restrict__ wp=(const uint4*)p.g1w2 + (kh*16*256 + col);
        const float* __restrict__ base=&s_z2[512 + kh*16*16];
        #pragma unroll 4
        for (int kb=0;kb<16;++kb){ kb16(wp,base+kb*16,a0,a1); wp+=256; }
      }
      *(v2f*)&s_p[1024 + kh*512 + col*2] = (v2f){a0,a1};
      a0=0.f;a1=0.f;
      {
        const uint4* __restrict__ wp=(const uint4*)p.g2w2 + (kh*16*256 + col);
        const float* __restrict__ base=&s_z2[1024 + kh*16*16];
        #pragma unroll 4
        for (int kb=0;kb<16;++kb){ kb16(wp,base+kb*16,a0,a1); wp+=256; }
      }
      *(v2f*)&s_p[2048 + kh*512 + col*2] = (v2f){a0,a1};
    }
    __syncthreads();                               // B11

    // ================ P10: mem update + x(t+1) refresh ================
    {
      float ch  = s_b6[3][col] + s_p[col*2+rr]      + s_p[512+col*2+rr];
      float gm1 = s_b6[4][col] + s_p[1024+col*2+rr] + s_p[1536+col*2+rr];
      float gm2 = s_b6[5][col] + s_p[2048+col*2+rr] + s_p[2560+col*2+rr];
      float mo = s_mem[rr*256+col];
      s_mem[rr*256+col] = sigf(gm1)*mo + sigf(gm2)*tanhf(ch);
    }
    if (t+1 < TSTEPS){
      const float* __restrict__ xb = p.x + (size_t)(t+1)*NBATCH*DX;
      int f0 = xfeat(tid>>1);
      if (f0>=0) s_x2[tid] = xb[(size_t)(n0+(tid&1))*DX + f0];
      int i2 = tid+512;
      if (i2 < 848){
        int f1 = xfeat(i2>>1);
        if (f1>=0) s_x2[i2] = xb[(size_t)(n0+(i2&1))*DX + f1];
      }
    }
    __syncthreads();                               // B12
  }

  // ================ output MLP (K=640, 2-way kh) ================
  for (int i=tid;i<1280;i+=512){
    int j=i>>1, r=i&1;
    float v = (j<384)? s_h2[j>>7][(j&127)*2+r] : s_mem[r*256 + (j-384)];
    s_last[i]=v;
  }
  __syncthreads();
  {
    float a0=0.f,a1=0.f;
    const uint4* __restrict__ wp=(const uint4*)p.ow1 + (kh*40*256 + col);
    const float* __restrict__ base=&s_last[kh*40*16];
    #pragma unroll 4
    for (int kb=0;kb<40;++kb){ kb16(wp,base+kb*16,a0,a1); wp+=256; }
    *(v2f*)&s_p[kh*512 + col*2] = (v2f){a0,a1};
  }
  __syncthreads();
  {
    float z = p.ob1[col] + s_p[col*2+rr] + s_p[512+col*2+rr];
    float pp = fmaxf(z,0.f)*p.ow2[col];
    for (int off=32; off; off>>=1) pp+=__shfl_down(pp,off);
    if ((tid&63)==0) s_red[tid>>6]=pp;
    __syncthreads();
    if (tid==0)   p.out[n0]   = s_red[0]+s_red[1]+s_red[2]+s_red[3]+p.ob2[0];
    if (tid==256) p.out[n0+1] = s_red[4]+s_red[5]+s_red[6]+s_red[7]+p.ob2[0];
  }
}

extern "C" void kernel_launch(void* const* d_in, const int* in_sizes, int n_in,
                              void* d_out, int out_size, void* d_ws, size_t ws_size,
                              hipStream_t stream){
  u16* ws = (u16*)d_ws;
  struct M { int src; size_t off; int OUT, IN, INP; };
  const M mats[15] = {
    { 5,       0, 512,  300, 304},  // Wih_l
    { 6,  155648, 512,  128, 128},  // Whh_l
    { 9,  221184, 512,   74,  80},  // Wih_a
    {10,  262144, 512,  128, 128},  // Whh_a
    {13,  327680, 512,   35,  40},  // Wih_v
    {14,  348160, 512,  128, 128},  // Whh_v
    {17,  413696, 256,  768, 768},  // att1_W1
    {19,  610304, 768,  256, 256},  // att1_W2
    {21,  806912, 256,  768, 768},  // att2_W1
    {23, 1003520, 256,  256, 256},  // att2_W2
    {25, 1069056, 256, 1024,1024},  // g1_W1
    {27, 1331200, 256,  256, 256},  // g1_W2
    {29, 1396736, 256, 1024,1024},  // g2_W1
    {31, 1658880, 256,  256, 256},  // g2_W2
    {33, 1724416, 256,  640, 640},  // out_W1
  };
  for (int i=0;i<15;i++){
    int total = mats[i].OUT*mats[i].INP;
    cast_tile8<<<(total+255)/256, 256, 0, stream>>>(
        (const float*)d_in[mats[i].src], ws + mats[i].off,
        mats[i].OUT, mats[i].IN, mats[i].INP);
  }

  P p;
  p.x     = (const float*)d_in[0];
  p.bih_l = (const float*)d_in[7];  p.bhh_l = (const float*)d_in[8];
  p.bih_a = (const float*)d_in[11]; p.bhh_a = (const float*)d_in[12];
  p.bih_v = (const float*)d_in[15]; p.bhh_v = (const float*)d_in[16];
  p.a1b1  = (const float*)d_in[18]; p.a1b2  = (const float*)d_in[20];
  p.a2b1  = (const float*)d_in[22]; p.a2b2  = (const float*)d_in[24];
  p.g1b1  = (const float*)d_in[26]; p.g1b2  = (const float*)d_in[28];
  p.g2b1  = (const float*)d_in[30]; p.g2b2  = (const float*)d_in[32];
  p.ob1   = (const float*)d_in[34]; p.ow2   = (const float*)d_in[35];
  p.ob2   = (const float*)d_in[36];
  p.ihl   = ws + 0;       p.hhl  = ws + 155648;
  p.iha   = ws + 221184;  p.hha  = ws + 262144;
  p.ihv   = ws + 327680;  p.hhv  = ws + 348160;
  p.a1w1  = ws + 413696;  p.a1w2 = ws + 610304;
  p.a2w1  = ws + 806912;  p.a2w2 = ws + 1003520;
  p.g1w1  = ws + 1069056; p.g1w2 = ws + 1331200;
  p.g2w1  = ws + 1396736; p.g2w2 = ws + 1658880;
  p.ow1   = ws + 1724416;
  p.out   = (float*)d_out;

  mfn_persistent<<<NBATCH/2, 512, 0, stream>>>(p);
}

// Round 9
// 32372.235 us; speedup vs baseline: 5.2524x; 1.2157x over previous
//
#include <hip/hip_runtime.h>
#include <math.h>

#define TSTEPS 512
#define NBATCH 256
#define DLL 300
#define DAA 74
#define DVV 35
#define DX  409
#define DH  128
#define DMEM 256
#define CST 768   // 6*DH

typedef unsigned short u16;
typedef unsigned int   u32;
typedef float v2f __attribute__((ext_vector_type(2)));

__device__ __forceinline__ float ulo(u32 u){ return __uint_as_float(u<<16); }
__device__ __forceinline__ float uhi(u32 u){ return __uint_as_float(u & 0xffff0000u); }
__device__ __forceinline__ float sigf(float x){ return 1.0f/(1.0f+expf(-x)); }

// 8k-tiled: dst[(kb*OUT + o)*8 + j] = bf16(src[o*IN + kb*8+j]) or 0 pad
__global__ void cast_tile8(const float* __restrict__ src, u16* __restrict__ dst,
                           int OUT, int IN, int INP){
  int e = blockIdx.x*blockDim.x + threadIdx.x;
  if (e >= OUT*INP) return;
  int j = e & 7;
  int q = e >> 3;
  int o = q % OUT;
  int kb = q / OUT;
  int k = kb*8 + j;
  float v = (k < IN) ? src[o*IN + k] : 0.f;
  u32 u = __float_as_uint(v);
  u32 r = (u + 0x7fffu + ((u>>16)&1u)) >> 16;   // RNE
  dst[e] = (u16)r;
}

struct P {
  const float* x;
  const float *bih_l,*bhh_l,*bih_a,*bhh_a,*bih_v,*bhh_v;
  const float *a1b1,*a1b2,*a2b1,*a2b2,*g1b1,*g1b2,*g2b1,*g2b2;
  const float *ob1,*ow2,*ob2;
  const u16 *ihl,*hhl,*iha,*hha,*ihv,*hhv;
  const u16 *a1w1,*a1w2,*a2w1,*a2w2,*g1w1,*g1w2,*g2w1,*g2w2,*ow1;
  float* out;
};

// one 8k tile: 8 bf16 weights (one col) x acts[16] (8k x 2 rows interleaved) -> 2 accs
__device__ __forceinline__ void kb16(uint4 w, const float* __restrict__ ap,
                                     float &a0, float &a1){
  float4 x0=*(const float4*)ap, x1=*(const float4*)(ap+4),
         x2=*(const float4*)(ap+8), x3=*(const float4*)(ap+12);
  a0 += x0.x*ulo(w.x); a1 += x0.y*ulo(w.x);
  a0 += x0.z*uhi(w.x); a1 += x0.w*uhi(w.x);
  a0 += x1.x*ulo(w.y); a1 += x1.y*ulo(w.y);
  a0 += x1.z*uhi(w.y); a1 += x1.w*uhi(w.y);
  a0 += x2.x*ulo(w.z); a1 += x2.y*ulo(w.z);
  a0 += x2.z*uhi(w.z); a1 += x2.w*uhi(w.z);
  a0 += x3.x*ulo(w.w); a1 += x3.y*ulo(w.w);
  a0 += x3.z*uhi(w.w); a1 += x3.w*uhi(w.w);
}

// 4-deep weight-prefetch ring; rolled loop keeps 4-8 uint4 loads in flight.
// NKB must be a multiple of 4, NKB >= 8.
template<int NKB, int WS>
__device__ __forceinline__ void sweep(const uint4* __restrict__ wp,
                                      const float* __restrict__ base,
                                      float &a0, float &a1){
  uint4 w0=wp[0], w1=wp[WS], w2=wp[2*WS], w3=wp[3*WS];
  const uint4* wn = wp + 4*WS;
  #pragma unroll 1
  for (int kb=0; kb+4<NKB; kb+=4){
    uint4 n0=wn[0], n1=wn[WS], n2=wn[2*WS], n3=wn[3*WS]; wn += 4*WS;
    kb16(w0, base+kb*16,    a0,a1);
    kb16(w1, base+kb*16+16, a0,a1);
    kb16(w2, base+kb*16+32, a0,a1);
    kb16(w3, base+kb*16+48, a0,a1);
    w0=n0; w1=n1; w2=n2; w3=n3;
  }
  kb16(w0, base+(NKB-4)*16, a0,a1);
  kb16(w1, base+(NKB-3)*16, a0,a1);
  kb16(w2, base+(NKB-2)*16, a0,a1);
  kb16(w3, base+(NKB-1)*16, a0,a1);
}

// padded x index -> feature index (or -1 for pad). L:[0,320) A:[320,416) V:[416,480)
__device__ __forceinline__ int xfeat(int i){
  if (i < 300) return i;
  if (i < 320) return -1;
  if (i < 394) return i-20;
  if (i < 416) return -1;
  if (i < 451) return i-42;
  return -1;
}

__global__ void __launch_bounds__(512, 2)
mfn_persistent(P p){
  __shared__ __align__(16) float s_x2[960];      // [i*2+r], i<480 padded (pads stay 0)
  __shared__ __align__(16) float s_h2[3][256];   // [m][u*2+r]
  __shared__ __align__(16) float s_c2[3][256];
  __shared__ __align__(16) float s_cstar[1536];  // [idx*2+r]
  __shared__ __align__(16) float s_z[512];       // [k*2+r]
  __shared__ __align__(16) float s_attm[2048];   // [idx*2+r], idx<1024 (att768|mem256)
  __shared__ __align__(16) float s_z2[1536];     // [(mat*256+col)*2+r]
  __shared__ __align__(16) float s_mem[512];     // [r*256+col]
  __shared__ __align__(16) float s_p[3072];      // gates / partials
  __shared__ __align__(16) float s_last[1280];   // [j*2+r]
  __shared__ __align__(16) float s_a1b1[256];
  __shared__ __align__(16) float s_a1b2[768];
  __shared__ __align__(16) float s_b6[6][256];   // a2b1,g1b1,g2b1,a2b2,g1b2,g2b2
  __shared__ float s_red[16];

  const int tid = threadIdx.x;
  const int n0  = blockIdx.x*2;
  const int col = tid&255, rr = tid>>8, kh = tid>>8;

  // LSTM biases in registers (1 col/thread in P1)
  const float bLg = p.bih_l[tid]+p.bhh_l[tid];
  const float bAg = p.bih_a[tid]+p.bhh_a[tid];
  const float bVg = p.bih_v[tid]+p.bhh_v[tid];

  // ---- init ----
  if (tid < 256){
    s_a1b1[tid]=p.a1b1[tid];
    s_b6[0][tid]=p.a2b1[tid]; s_b6[1][tid]=p.g1b1[tid]; s_b6[2][tid]=p.g2b1[tid];
    s_b6[3][tid]=p.a2b2[tid]; s_b6[4][tid]=p.g1b2[tid]; s_b6[5][tid]=p.g2b2[tid];
  }
  for (int i=tid;i<768;i+=512){
    s_a1b2[i]=p.a1b2[i];
    (&s_h2[0][0])[i]=0.f; (&s_c2[0][0])[i]=0.f;
  }
  s_mem[tid]=0.f;
  for (int i2=tid;i2<960;i2+=512){
    float v=0.f; int f=xfeat(i2>>1);
    if (f>=0) v = p.x[(size_t)(n0+(i2&1))*DX + f];
    s_x2[i2]=v;
  }
  __syncthreads();

  for (int t=0; t<TSTEPS; t++){
    // ================ P1: LSTM gates (1 col/thread, coherent full-K sweeps) ========
    {
      float a0,a1;
      a0=0.f; a1=0.f;
      sweep<40,512>((const uint4*)p.ihl + tid, &s_x2[0],   a0,a1);
      sweep<16,512>((const uint4*)p.hhl + tid, &s_h2[0][0],a0,a1);
      *(v2f*)&s_p[tid*2] = (v2f){a0+bLg, a1+bLg};
      a0=0.f; a1=0.f;
      sweep<12,512>((const uint4*)p.iha + tid, &s_x2[640], a0,a1);
      sweep<16,512>((const uint4*)p.hha + tid, &s_h2[1][0],a0,a1);
      *(v2f*)&s_p[1024 + tid*2] = (v2f){a0+bAg, a1+bAg};
      a0=0.f; a1=0.f;
      sweep< 8,512>((const uint4*)p.ihv + tid, &s_x2[832], a0,a1);
      sweep<16,512>((const uint4*)p.hhv + tid, &s_h2[2][0],a0,a1);
      *(v2f*)&s_p[2048 + tid*2] = (v2f){a0+bVg, a1+bVg};
    }
    __syncthreads();                               // B1

    // ================ P2: LSTM activations (768 tasks) ================
    for (int task=tid; task<768; task+=512){
      int m=task>>8, rem=task&255, u=rem>>1, r=rem&1;
      const float* pm = s_p + m*1024;
      float g0 = pm[u*2+r];
      float g1 = pm[(128+u)*2+r];
      float g2 = pm[(256+u)*2+r];
      float g3 = pm[(384+u)*2+r];
      float ig=sigf(g0), fg=sigf(g1), gg=tanhf(g2), og=sigf(g3);
      float co=s_c2[m][u*2+r];
      float c = fg*co + ig*gg;
      float h = og*tanhf(c);
      s_c2[m][u*2+r]=c; s_h2[m][u*2+r]=h;
      s_cstar[(m*128+u)*2+r]     = co;
      s_cstar[(384+m*128+u)*2+r] = c;
    }
    __syncthreads();                               // B2

    // ================ P3: att1_W1 (K=768, OUT=256, 2-way kh split) ================
    {
      float a0=0.f,a1=0.f;
      sweep<48,256>((const uint4*)p.a1w1 + (kh*48*256 + col), &s_cstar[kh*768], a0,a1);
      *(v2f*)&s_p[kh*512 + col*2] = (v2f){a0,a1};
    }
    __syncthreads();                               // B3

    // ================ P4: z1 finalize ================
    {
      float z = s_a1b1[col] + s_p[col*2+rr] + s_p[512+col*2+rr];
      s_z[col*2+rr] = fmaxf(z,0.f);
    }
    __syncthreads();                               // B4

    // ================ P5: att1_W2 (K=256, OUT=768; 3 sequential col-streams) ========
    {
      const uint4* wb=(const uint4*)p.a1w2 + (kh*16*768 + col);
      const float* base=&s_z[kh*256];
      float a0=0.f,a1=0.f,b0=0.f,b1=0.f,c0=0.f,c1=0.f;
      sweep<16,768>(wb,     base, a0,a1);
      sweep<16,768>(wb+256, base, b0,b1);
      sweep<16,768>(wb+512, base, c0,c1);
      *(v2f*)&s_p[kh*1536 + col*2]         = (v2f){a0,a1};
      *(v2f*)&s_p[kh*1536 + (256+col)*2]   = (v2f){b0,b1};
      *(v2f*)&s_p[kh*1536 + (512+col)*2]   = (v2f){c0,c1};
    }
    __syncthreads();                               // B5

    // ================ softmax + attended ================
    {
      float s0 = s_a1b2[col]     + s_p[col*2+rr]       + s_p[1536+col*2+rr];
      float s1 = s_a1b2[256+col] + s_p[(256+col)*2+rr] + s_p[1536+(256+col)*2+rr];
      float s2 = s_a1b2[512+col] + s_p[(512+col)*2+rr] + s_p[1536+(512+col)*2+rr];
      float mx=fmaxf(fmaxf(s0,s1),s2);
      for (int off=32; off; off>>=1) mx=fmaxf(mx,__shfl_down(mx,off));
      if ((tid&63)==0) s_red[tid>>6]=mx;
      __syncthreads();                             // B6
      float m = fmaxf(fmaxf(s_red[rr*4],s_red[rr*4+1]),fmaxf(s_red[rr*4+2],s_red[rr*4+3]));
      float e0=expf(s0-m), e1=expf(s1-m), e2=expf(s2-m);
      float ss=e0+e1+e2;
      for (int off=32; off; off>>=1) ss+=__shfl_down(ss,off);
      if ((tid&63)==0) s_red[8+(tid>>6)]=ss;
      s_attm[(768+col)*2+rr] = s_mem[rr*256+col];
      __syncthreads();                             // B7
      float inv=1.f/(s_red[8+rr*4]+s_red[8+rr*4+1]+s_red[8+rr*4+2]+s_red[8+rr*4+3]);
      s_attm[col*2+rr]       = e0*inv*s_cstar[col*2+rr];
      s_attm[(256+col)*2+rr] = e1*inv*s_cstar[(256+col)*2+rr];
      s_attm[(512+col)*2+rr] = e2*inv*s_cstar[(512+col)*2+rr];
    }
    __syncthreads();                               // B8

    // ================ P7: a2w1 (K=768) / g1w1,g2w1 (K=1024), 2-way kh ================
    {
      float a0,a1;
      a0=0.f;a1=0.f;
      sweep<48,256>((const uint4*)p.a2w1 + (kh*48*256 + col), &s_attm[kh*768], a0,a1);
      *(v2f*)&s_p[kh*512 + col*2] = (v2f){a0,a1};
      a0=0.f;a1=0.f;
      sweep<64,256>((const uint4*)p.g1w1 + (kh*64*256 + col), &s_attm[kh*1024], a0,a1);
      *(v2f*)&s_p[1024 + kh*512 + col*2] = (v2f){a0,a1};
      a0=0.f;a1=0.f;
      sweep<64,256>((const uint4*)p.g2w1 + (kh*64*256 + col), &s_attm[kh*1024], a0,a1);
      *(v2f*)&s_p[2048 + kh*512 + col*2] = (v2f){a0,a1};
    }
    __syncthreads();                               // B9

    // ================ P8: z2 finalize (1536 tasks) ================
    for (int i=tid;i<1536;i+=512){
      int mat=i>>9, rem=i&511, c2=rem>>1, r=rem&1;
      const float* q = s_p + mat*1024;
      float v = s_b6[mat][c2] + q[c2*2+r] + q[512+c2*2+r];
      s_z2[(mat*256+c2)*2+r] = fmaxf(v,0.f);
    }
    __syncthreads();                               // B10

    // ================ P9: a2w2/g1w2/g2w2 (K=256 each, 2-way kh) ================
    {
      float a0,a1;
      a0=0.f;a1=0.f;
      sweep<16,256>((const uint4*)p.a2w2 + (kh*16*256 + col), &s_z2[kh*256], a0,a1);
      *(v2f*)&s_p[kh*512 + col*2] = (v2f){a0,a1};
      a0=0.f;a1=0.f;
      sweep<16,256>((const uint4*)p.g1w2 + (kh*16*256 + col), &s_z2[512+kh*256], a0,a1);
      *(v2f*)&s_p[1024 + kh*512 + col*2] = (v2f){a0,a1};
      a0=0.f;a1=0.f;
      sweep<16,256>((const uint4*)p.g2w2 + (kh*16*256 + col), &s_z2[1024+kh*256], a0,a1);
      *(v2f*)&s_p[2048 + kh*512 + col*2] = (v2f){a0,a1};
    }
    __syncthreads();                               // B11

    // ================ P10: mem update + x(t+1) refresh ================
    {
      float ch  = s_b6[3][col] + s_p[col*2+rr]      + s_p[512+col*2+rr];
      float gm1 = s_b6[4][col] + s_p[1024+col*2+rr] + s_p[1536+col*2+rr];
      float gm2 = s_b6[5][col] + s_p[2048+col*2+rr] + s_p[2560+col*2+rr];
      float mo = s_mem[rr*256+col];
      s_mem[rr*256+col] = sigf(gm1)*mo + sigf(gm2)*tanhf(ch);
    }
    if (t+1 < TSTEPS){
      const float* __restrict__ xb = p.x + (size_t)(t+1)*NBATCH*DX;
      int f0 = xfeat(tid>>1);
      if (f0>=0) s_x2[tid] = xb[(size_t)(n0+(tid&1))*DX + f0];
      int i2 = tid+512;
      if (i2 < 960){
        int f1 = xfeat(i2>>1);
        if (f1>=0) s_x2[i2] = xb[(size_t)(n0+(i2&1))*DX + f1];
      }
    }
    __syncthreads();                               // B12
  }

  // ================ output MLP (K=640, 2-way kh) ================
  for (int i=tid;i<1280;i+=512){
    int j=i>>1, r=i&1;
    float v = (j<384)? s_h2[j>>7][(j&127)*2+r] : s_mem[r*256 + (j-384)];
    s_last[i]=v;
  }
  __syncthreads();
  {
    float a0=0.f,a1=0.f;
    sweep<40,256>((const uint4*)p.ow1 + (kh*40*256 + col), &s_last[kh*640], a0,a1);
    *(v2f*)&s_p[kh*512 + col*2] = (v2f){a0,a1};
  }
  __syncthreads();
  {
    float z = p.ob1[col] + s_p[col*2+rr] + s_p[512+col*2+rr];
    float pp = fmaxf(z,0.f)*p.ow2[col];
    for (int off=32; off; off>>=1) pp+=__shfl_down(pp,off);
    if ((tid&63)==0) s_red[tid>>6]=pp;
    __syncthreads();
    if (tid==0)   p.out[n0]   = s_red[0]+s_red[1]+s_red[2]+s_red[3]+p.ob2[0];
    if (tid==256) p.out[n0+1] = s_red[4]+s_red[5]+s_red[6]+s_red[7]+p.ob2[0];
  }
}

extern "C" void kernel_launch(void* const* d_in, const int* in_sizes, int n_in,
                              void* d_out, int out_size, void* d_ws, size_t ws_size,
                              hipStream_t stream){
  u16* ws = (u16*)d_ws;
  struct M { int src; size_t off; int OUT, IN, INP; };
  const M mats[15] = {
    { 5,       0, 512,  300, 320},  // Wih_l
    { 6,  163840, 512,  128, 128},  // Whh_l
    { 9,  229376, 512,   74,  96},  // Wih_a
    {10,  278528, 512,  128, 128},  // Whh_a
    {13,  344064, 512,   35,  64},  // Wih_v
    {14,  376832, 512,  128, 128},  // Whh_v
    {17,  442368, 256,  768, 768},  // att1_W1
    {19,  638976, 768,  256, 256},  // att1_W2
    {21,  835584, 256,  768, 768},  // att2_W1
    {23, 1032192, 256,  256, 256},  // att2_W2
    {25, 1097728, 256, 1024,1024},  // g1_W1
    {27, 1359872, 256,  256, 256},  // g1_W2
    {29, 1425408, 256, 1024,1024},  // g2_W1
    {31, 1687552, 256,  256, 256},  // g2_W2
    {33, 1753088, 256,  640, 640},  // out_W1
  };
  for (int i=0;i<15;i++){
    int total = mats[i].OUT*mats[i].INP;
    cast_tile8<<<(total+255)/256, 256, 0, stream>>>(
        (const float*)d_in[mats[i].src], ws + mats[i].off,
        mats[i].OUT, mats[i].IN, mats[i].INP);
  }

  P p;
  p.x     = (const float*)d_in[0];
  p.bih_l = (const float*)d_in[7];  p.bhh_l = (const float*)d_in[8];
  p.bih_a = (const float*)d_in[11]; p.bhh_a = (const float*)d_in[12];
  p.bih_v = (const float*)d_in[15]; p.bhh_v = (const float*)d_in[16];
  p.a1b1  = (const float*)d_in[18]; p.a1b2  = (const float*)d_in[20];
  p.a2b1  = (const float*)d_in[22]; p.a2b2  = (const float*)d_in[24];
  p.g1b1  = (const float*)d_in[26]; p.g1b2  = (const float*)d_in[28];
  p.g2b1  = (const float*)d_in[30]; p.g2b2  = (const float*)d_in[32];
  p.ob1   = (const float*)d_in[34]; p.ow2   = (const float*)d_in[35];
  p.ob2   = (const float*)d_in[36];
  p.ihl   = ws + 0;       p.hhl  = ws + 163840;
  p.iha   = ws + 229376;  p.hha  = ws + 278528;
  p.ihv   = ws + 344064;  p.hhv  = ws + 376832;
  p.a1w1  = ws + 442368;  p.a1w2 = ws + 638976;
  p.a2w1  = ws + 835584;  p.a2w2 = ws + 1032192;
  p.g1w1  = ws + 1097728; p.g1w2 = ws + 1359872;
  p.g2w1  = ws + 1425408; p.g2w2 = ws + 1687552;
  p.ow1   = ws + 1753088;
  p.out   = (float*)d_out;

  mfn_persistent<<<NBATCH/2, 512, 0, stream>>>(p);
}